// Round 10
// baseline (270.835 us; speedup 1.0000x reference)
//
#include <hip/hip_runtime.h>

// Problem constants
#define NITEMS 50000
#define EMBD   16
#define NSLATE 10
#define HIDD   512
#define LATD   64
#define RESPD  1024
#define BATCH  256
#define KCH    120   // pool k-chunks: 3125 ksteps (=50000/16) split 5x27 + 115x26
#define LOG2E  1.44269504088896340736f
#define SHIFT  64.0f  // fixed log2-domain shift: s = sum exp2(x*log2e - 64)

// MFMA scoring: logits = rx[2560x16] @ emb^T[16x50000] via v_mfma_f32_32x32x16_bf16.
// C=2 col-groups/wave, IC=224 chunks -> 2240 blocks.
#define NCOL   2560   // BATCH*NSLATE output columns
#define NT     1563   // ceil(50000/32) item tiles (last tile has 16 pad rows)
#define NPAD   50016  // NT*32 padded items
#define IC     224    // item chunks (grid.y)
#define TPC    7      // tiles per chunk: 224*7 = 1568 >= 1563

// d_out layout (float): z_mean[256*64] | z_log_var[256*64] | recon_slate[256*10] | recon_resp[256*10]
#define OUT_ZM 0
#define OUT_ZLV 16384
#define OUT_RS 32768
#define OUT_RR 35328

// ws layout (floats), with time-overlays (all dispatches stream-ordered):
//   [0 .. 589824)        x[307200] + dz[282624]  (build_x -> enc / d1)
//                        OVERLAY p2[8*40960=327680] (gemm_d2 -> rx_prep)
//   [0 .. 573440)        OVERLAY score S-partials ps[224*2560] (score_mfma -> score_final)
//   [573440 .. 578560)   OVERLAY keys[2560 u64] packed (mono(m)<<32 | 2047-tile)
//   [589824 .. 1114112)  pool partials pp [120kc*256*17 = 522240] (pool_mfma -> build_x)
//                        OVERLAY part[4*131072] (enc->mulv_z, d1->gemm_d2)
//   [1114112 .. 1155072) rx[40960] f32, LOG2E-scaled (rx_prep -> score_final)
//   [1155072 .. 1216512) rx bf16 3-way split rx0/rx1/rx2 [3*40960 ushort]
//   --- extension (guarded by ws_size >= WS_NEED bytes; round-9 profile showed the
//       harness fills a 256 MiB d_ws, so the old 4.87MB cap was self-imposed) ---
//   [1216512 .. 1616640) es0 [50016*16 ushort] emb split level 0 (emb_split -> score/fix)
//   [1616640 .. 2016768) es1
//   [2016768 .. 2416896) es2
// WS_NEED = 2416896 floats = 9.67 MB; fallback path (PRE=0) = round-9 inline split.
#define WS_X    0
#define WS_DZ   307200
#define WS_P2   0
#define WS_PS   0
#define WS_KEY  573440
#define WS_PP   589824
#define WS_PART 589824
#define WS_RX   1114112
#define WS_RXS0 1155072
#define WS_RXS1 1175552
#define WS_RXS2 1196032
#define WS_ES0  1216512
#define WS_ES1  1616640
#define WS_ES2  2016768
#define WS_NEED ((size_t)2416896 * 4)

typedef __attribute__((ext_vector_type(8))) short bfrag;    // 8 bf16 = 4 VGPR (A/B operand)
typedef __attribute__((ext_vector_type(16))) float f32x16;  // C/D operand

// round-to-nearest-even f32 -> bf16, returned as f32 with low mantissa zeroed
__device__ __forceinline__ float bfround(float v) {
  unsigned u = __float_as_uint(v);
  unsigned r = (u + 0x7FFFu + ((u >> 16) & 1u)) & 0xFFFF0000u;
  return __uint_as_float(r);
}

// monotone bijection f32 -> u32 (x < y  <=>  mono(x) < mono(y))
__device__ __forceinline__ unsigned mono32(float f) {
  unsigned u = __float_as_uint(f);
  return (u & 0x80000000u) ? ~u : (u | 0x80000000u);
}

#define FMAX3(a, b, c) fmaxf(fmaxf((a), (b)), (c))

// Exact truncation 3-way split of one f32 pair into packed bf16 words.
__device__ __forceinline__ void split3(float v0, float v1,
    unsigned& o0, unsigned& o1, unsigned& o2) {
  unsigned u0 = __float_as_uint(v0), u1 = __float_as_uint(v1);
  o0 = (u0 >> 16) | (u1 & 0xFFFF0000u);
  float r0 = v0 - __uint_as_float(u0 & 0xFFFF0000u);   // exact
  float r1 = v1 - __uint_as_float(u1 & 0xFFFF0000u);   // exact
  unsigned w0 = __float_as_uint(r0), w1 = __float_as_uint(r1);
  o1 = (w0 >> 16) | (w1 & 0xFFFF0000u);
  float q0 = r0 - __uint_as_float(w0 & 0xFFFF0000u);   // exact, fits bf16
  float q1 = r1 - __uint_as_float(w1 & 0xFFFF0000u);   // exact, fits bf16
  o2 = (__float_as_uint(q0) >> 16) | (__float_as_uint(q1) & 0xFFFF0000u);
}

// Precompute emb 3-way split, padded to NPAD rows with -128 (split: -128, 0, 0 --
// bitwise identical to the previous in-loop pad handling). 50016*8 pair-slots.
__global__ __launch_bounds__(256) void emb_split(const float* __restrict__ emb,
    unsigned* __restrict__ es0, unsigned* __restrict__ es1, unsigned* __restrict__ es2) {
  int idx = blockIdx.x * 256 + threadIdx.x;   // pair index: item*8 + jp
  if (idx >= NPAD * 8) return;
  int item = idx >> 3, jp = idx & 7;
  float v0 = -128.f, v1 = -128.f;
  if (item < NITEMS) {
    v0 = emb[(size_t)item * 16 + 2 * jp];
    v1 = emb[(size_t)item * 16 + 2 * jp + 1];
  }
  unsigned o0, o1, o2;
  split3(v0, v1, o0, o1, o2);
  es0[idx] = o0; es1[idx] = o1; es2[idx] = o2;
}

// MFMA pooling: user[256][17] = U[256x50000] @ [emb | 1] via v_mfma_f32_32x32x16_bf16.
// U is EXACT in bf16 (0/1); emb exact 3-way trunc split (all terms kept).
// Partials [kc][256][17] -> pp. (Round-9: removed pool from top-5.)
__global__ __launch_bounds__(256) void pool_mfma(const int* __restrict__ u,
    const float* __restrict__ emb, float* __restrict__ pp) {
  int t = threadIdx.x;
  int w = t >> 6, l = t & 63;
  int ln = l & 31, hf = l >> 5;
  int rt = blockIdx.x * 4 + w;     // 0..7 row tile (32 batches each)
  int kc = blockIdx.y;             // 0..119 k-chunks
  int row = rt * 32 + ln;
  int ks = kc * 26 + min(kc, 5);
  int ke = ks + 26 + (kc < 5 ? 1 : 0);
  const int* uRow = u + (size_t)row * NITEMS + hf * 8;
  f32x16 acc;
  #pragma unroll
  for (int i = 0; i < 16; ++i) acc[i] = 0.f;
  #pragma unroll 1
  for (int k0 = ks; k0 < ke; ++k0) {
    const int4* ap = (const int4*)(uRow + k0 * 16);
    int4 a0 = ap[0], a1 = ap[1];
    union { bfrag f; unsigned ui[4]; } A;
    A.ui[0] = (a0.x ? 0x3F80u : 0u) | (a0.y ? 0x3F800000u : 0u);
    A.ui[1] = (a0.z ? 0x3F80u : 0u) | (a0.w ? 0x3F800000u : 0u);
    A.ui[2] = (a1.x ? 0x3F80u : 0u) | (a1.y ? 0x3F800000u : 0u);
    A.ui[3] = (a1.z ? 0x3F80u : 0u) | (a1.w ? 0x3F800000u : 0u);
    union { bfrag f; unsigned ui[4]; } B0, B1, B2;
    if (ln < 16) {
      const float* ep = emb + (size_t)(k0 * 16 + hf * 8) * 16 + ln;
      #pragma unroll
      for (int j = 0; j < 4; ++j)
        split3(ep[(2 * j) * 16], ep[(2 * j + 1) * 16], B0.ui[j], B1.ui[j], B2.ui[j]);
    } else {
      unsigned c0 = (ln == 16) ? 0x3F803F80u : 0u;
      #pragma unroll
      for (int j = 0; j < 4; ++j) { B0.ui[j] = c0; B1.ui[j] = 0u; B2.ui[j] = 0u; }
    }
    acc = __builtin_amdgcn_mfma_f32_32x32x16_bf16(A.f, B2.f, acc, 0, 0, 0);
    acc = __builtin_amdgcn_mfma_f32_32x32x16_bf16(A.f, B1.f, acc, 0, 0, 0);
    acc = __builtin_amdgcn_mfma_f32_32x32x16_bf16(A.f, B0.f, acc, 0, 0, 0);
  }
  if (ln < 17) {
    float* dst = pp + (size_t)kc * 4352 + (size_t)(rt * 32) * 17 + ln;
    #pragma unroll
    for (int g = 0; g < 4; ++g)
      #pragma unroll
      for (int q = 0; q < 4; ++q) {
        int r = q + 8 * g + 4 * hf;
        dst[r * 17] = acc[g * 4 + q];
      }
  }
}

// Sum 120 k-chunk partials per b; build x = [slate(160)|user(16)|resp(1024)],
// dz[64:1104] = [user|resp].
__global__ __launch_bounds__(256) void build_x(const float* __restrict__ pp,
    const int* __restrict__ slate, const float* __restrict__ resp,
    const float* __restrict__ emb, float* __restrict__ x, float* __restrict__ dz) {
  __shared__ float fin[17];
  int b = blockIdx.x, t = threadIdx.x;
  if (t < 17) {
    float a = 0.f;
    const float* p = pp + (size_t)b * 17 + t;
    #pragma unroll 8
    for (int kc = 0; kc < KCH; ++kc) a += p[(size_t)kc * 4352];
    fin[t] = a;
  }
  __syncthreads();
  float inv = 1.0f / fin[16];
  if (t < 16) {
    float uv = fin[t] * inv;
    x[b * 1200 + 160 + t] = uv;
    dz[b * 1104 + 64 + t] = uv;
  }
  if (t >= 32 && t < 192) {
    int i = t - 32;
    int k = i >> 4, e = i & 15;
    int it = slate[b * 10 + k];
    x[b * 1200 + i] = emb[(size_t)it * 16 + e];
  }
  for (int i = t; i < 1024; i += 256) {
    float r = resp[b * 1024 + i];
    x[b * 1200 + 176 + i] = r;
    dz[b * 1104 + 80 + i] = r;
  }
}

// Split-K partial GEMM: P[z][M,N] = A[M,ks:ke] @ B[N,ks:ke]^T
__global__ __launch_bounds__(256) void gemm64(const float* __restrict__ A,
    const float* __restrict__ B, float* __restrict__ P, int M, int N, int K, int kChunk) {
  __shared__ float As[16][68];  // As[kk][m]
  __shared__ float Bs[16][68];  // Bs[kk][n]
  int tid = threadIdx.x;
  int m0 = blockIdx.y * 64, n0 = blockIdx.x * 64;
  int ks = blockIdx.z * kChunk;
  int ke = ks + kChunk; if (ke > K) ke = K;
  int sr = tid >> 2;          // 0..63
  int sc = (tid & 3) * 4;     // 0,4,8,12
  int tx = tid & 15, ty = tid >> 4;
  float acc[4][4];
  #pragma unroll
  for (int i = 0; i < 4; ++i)
    #pragma unroll
    for (int j = 0; j < 4; ++j) acc[i][j] = 0.f;
  for (int k0 = ks; k0 < ke; k0 += 16) {
    float4 av = make_float4(0.f, 0.f, 0.f, 0.f);
    float4 bv = make_float4(0.f, 0.f, 0.f, 0.f);
    if (k0 + sc < ke)
      av = *(const float4*)(A + (size_t)(m0 + sr) * K + k0 + sc);
    if (k0 + sc < ke && n0 + sr < N)
      bv = *(const float4*)(B + (size_t)(n0 + sr) * K + k0 + sc);
    __syncthreads();
    As[sc][sr] = av.x; As[sc + 1][sr] = av.y; As[sc + 2][sr] = av.z; As[sc + 3][sr] = av.w;
    Bs[sc][sr] = bv.x; Bs[sc + 1][sr] = bv.y; Bs[sc + 2][sr] = bv.z; Bs[sc + 3][sr] = bv.w;
    __syncthreads();
    #pragma unroll
    for (int kk = 0; kk < 16; ++kk) {
      float4 a4 = *(const float4*)&As[kk][4 * ty];
      float4 b4 = *(const float4*)&Bs[kk][4 * tx];
      float a[4] = {a4.x, a4.y, a4.z, a4.w};
      float b[4] = {b4.x, b4.y, b4.z, b4.w};
      #pragma unroll
      for (int i = 0; i < 4; ++i)
        #pragma unroll
        for (int j = 0; j < 4; ++j) acc[i][j] = fmaf(a[i], b[j], acc[i][j]);
    }
  }
  float* Pz = P + (size_t)blockIdx.z * M * N;
  #pragma unroll
  for (int i = 0; i < 4; ++i) {
    int m = m0 + 4 * ty + i, n = n0 + 4 * tx;
    if (n < N)
      *(float4*)(Pz + (size_t)m * N + n) = make_float4(acc[i][0], acc[i][1], acc[i][2], acc[i][3]);
  }
}

// h = relu(sum_s part[s] + b_enc); z_mean/z_log_var -> out; z -> dz[0:64]
__global__ __launch_bounds__(128) void mulv_z_kernel(const float* __restrict__ part,
    const float* __restrict__ benc,
    const float* __restrict__ Wmu, const float* __restrict__ bmu,
    const float* __restrict__ Wlv, const float* __restrict__ blv,
    const float* __restrict__ eps, float* __restrict__ out, float* __restrict__ dz) {
  __shared__ __align__(16) float hs[512];
  __shared__ float zms[64], zlvs[64];
  int b = blockIdx.x, t = threadIdx.x;
  for (int i = t; i < 512; i += 128) {
    float a = benc[i];
    #pragma unroll
    for (int s = 0; s < 4; ++s) a += part[(size_t)s * 131072 + b * 512 + i];
    hs[i] = fmaxf(a, 0.f);
  }
  __syncthreads();
  const float* Wr = (t < 64) ? (Wmu + (size_t)t * 512) : (Wlv + (size_t)(t - 64) * 512);
  float bias = (t < 64) ? bmu[t] : blv[t - 64];
  const float4* w4 = (const float4*)Wr;
  const float4* h4 = (const float4*)hs;
  float a0 = 0.f, a1 = 0.f, a2 = 0.f, a3 = 0.f;
  #pragma unroll 4
  for (int i = 0; i < 128; ++i) {
    float4 w = w4[i], hv = h4[i];
    a0 = fmaf(w.x, hv.x, a0); a1 = fmaf(w.y, hv.y, a1);
    a2 = fmaf(w.z, hv.z, a2); a3 = fmaf(w.w, hv.w, a3);
  }
  float acc = (a0 + a1) + (a2 + a3) + bias;
  if (t < 64) { out[OUT_ZM + b * 64 + t] = acc; zms[t] = acc; }
  else        { out[OUT_ZLV + b * 64 + (t - 64)] = acc; zlvs[t - 64] = acc; }
  __syncthreads();
  if (t < 64) {
    float zv = fmaf(eps[b * 64 + t], __builtin_amdgcn_exp2f(0.7213475204444817f * zlvs[t]), zms[t]);
    dz[b * 1104 + t] = zv;
  }
}

// d2 split-K GEMM with reduce-on-load: A[m][k] = relu(sum_s part[s][m*512+k] + b_d1[k]),
// P2[z] = A[:, z*64:(z+1)*64] @ W_d2[:, same]^T. Grid (3,4,8). Bias/relu/scale in rx_prep.
__global__ __launch_bounds__(256) void gemm_d2(const float* __restrict__ part,
    const float* __restrict__ bd1, const float* __restrict__ W, float* __restrict__ p2) {
  __shared__ float As[16][68];
  __shared__ float Bs[16][68];
  const int N = 160;
  int tid = threadIdx.x;
  int m0 = blockIdx.y * 64, n0 = blockIdx.x * 64;
  int ks = blockIdx.z * 64, ke = ks + 64;
  int sr = tid >> 2, sc = (tid & 3) * 4;
  int tx = tid & 15, ty = tid >> 4;
  float acc[4][4];
  #pragma unroll
  for (int i = 0; i < 4; ++i)
    #pragma unroll
    for (int j = 0; j < 4; ++j) acc[i][j] = 0.f;
  for (int k0 = ks; k0 < ke; k0 += 16) {
    int col = k0 + sc;
    const float* p = part + (size_t)(m0 + sr) * 512 + col;
    float4 a0 = *(const float4*)(p);
    float4 a1 = *(const float4*)(p + 131072);
    float4 a2 = *(const float4*)(p + 262144);
    float4 a3 = *(const float4*)(p + 393216);
    float4 bb = *(const float4*)(bd1 + col);
    float4 av;
    av.x = fmaxf(a0.x + a1.x + a2.x + a3.x + bb.x, 0.f);
    av.y = fmaxf(a0.y + a1.y + a2.y + a3.y + bb.y, 0.f);
    av.z = fmaxf(a0.z + a1.z + a2.z + a3.z + bb.z, 0.f);
    av.w = fmaxf(a0.w + a1.w + a2.w + a3.w + bb.w, 0.f);
    float4 bv = make_float4(0.f, 0.f, 0.f, 0.f);
    if (n0 + sr < N)
      bv = *(const float4*)(W + (size_t)(n0 + sr) * 512 + col);
    __syncthreads();
    As[sc][sr] = av.x; As[sc + 1][sr] = av.y; As[sc + 2][sr] = av.z; As[sc + 3][sr] = av.w;
    Bs[sc][sr] = bv.x; Bs[sc + 1][sr] = bv.y; Bs[sc + 2][sr] = bv.z; Bs[sc + 3][sr] = bv.w;
    __syncthreads();
    #pragma unroll
    for (int kk = 0; kk < 16; ++kk) {
      float4 a4 = *(const float4*)&As[kk][4 * ty];
      float4 b4 = *(const float4*)&Bs[kk][4 * tx];
      float a[4] = {a4.x, a4.y, a4.z, a4.w};
      float b[4] = {b4.x, b4.y, b4.z, b4.w};
      #pragma unroll
      for (int i = 0; i < 4; ++i)
        #pragma unroll
        for (int j = 0; j < 4; ++j) acc[i][j] = fmaf(a[i], b[j], acc[i][j]);
    }
  }
  float* Pz = p2 + (size_t)blockIdx.z * 40960;
  #pragma unroll
  for (int i = 0; i < 4; ++i) {
    int m = m0 + 4 * ty + i, n = n0 + 4 * tx;
    if (n < N)
      *(float4*)(Pz + (size_t)m * 160 + n) = make_float4(acc[i][0], acc[i][1], acc[i][2], acc[i][3]);
  }
}

// Finish d2: rx = relu(sum_z p2 + b_d2) * LOG2E, 3-way bf16 split, and ZERO the
// per-col argmax keys (2560 u64; blockIdx covers b, t<10 covers the 10 slate cols).
__global__ __launch_bounds__(256) void rx_prep(const float* __restrict__ p2,
    const float* __restrict__ bd2, float* __restrict__ rx,
    unsigned short* __restrict__ rx0, unsigned short* __restrict__ rx1,
    unsigned short* __restrict__ rx2, unsigned long long* __restrict__ keys) {
  int b = blockIdx.x, t = threadIdx.x;
  if (t < 10) keys[b * 10 + t] = 0ULL;
  if (t >= 160) return;
  float a = bd2[t];
  #pragma unroll
  for (int z = 0; z < 8; ++z) a += p2[(size_t)z * 40960 + b * 160 + t];
  float v = fmaxf(a, 0.f) * LOG2E;
  rx[b * 160 + t] = v;
  int col = b * 10 + (t >> 4), e = t & 15;
  float f0 = bfround(v);
  float d1 = v - f0;            // exact (Sterbenz)
  float f1 = bfround(d1);
  float d2 = d1 - f1;           // exact
  float f2 = bfround(d2);
  rx0[col * 16 + e] = (unsigned short)(__float_as_uint(f0) >> 16);
  rx1[col * 16 + e] = (unsigned short)(__float_as_uint(f1) >> 16);
  rx2[col * 16 + e] = (unsigned short)(__float_as_uint(f2) >> 16);
}

// MFMA scoring: per wave TWO 32-col groups, TPC tiles/chunk, IC=224 chunks.
// PRE=1: A-fragments are 3x16B loads from the precomputed es0/es1/es2 arrays
// (emb_split) -- no in-loop split VALU, no NITEMS branch, loads pipeline past
// MFMAs. PRE=0: round-9 inline split (bitwise-identical values either way).
// Global (max, tile) via per-col packed atomicMax key = mono(m)<<32 | (2047-tile).
template<int PRE>
__global__ __launch_bounds__(256) void score_mfma(const float* __restrict__ emb,
    const unsigned short* __restrict__ rx0, const unsigned short* __restrict__ rx1,
    const unsigned short* __restrict__ rx2,
    const unsigned short* __restrict__ es0, const unsigned short* __restrict__ es1,
    const unsigned short* __restrict__ es2,
    float* __restrict__ ps, unsigned long long* __restrict__ keys) {
  int t = threadIdx.x;
  int w = t >> 6, l = t & 63;
  int ln = l & 31, hf = l >> 5;
  int pair = blockIdx.x * 4 + w;   // 0..39 column-pair groups
  int ic = blockIdx.y;             // 0..223 item chunks
  int colA = pair * 64 + ln;       // 0..2559
  int colB = colA + 32;
  size_t offA = (size_t)colA * 16 + hf * 8;
  size_t offB = (size_t)colB * 16 + hf * 8;
  bfrag bA0 = *(const bfrag*)(rx0 + offA);
  bfrag bA1 = *(const bfrag*)(rx1 + offA);
  bfrag bA2 = *(const bfrag*)(rx2 + offA);
  bfrag bB0 = *(const bfrag*)(rx0 + offB);
  bfrag bB1 = *(const bfrag*)(rx1 + offB);
  bfrag bB2 = *(const bfrag*)(rx2 + offB);
  float sA = 0.f, sB = 0.f;
  float mA = -3.402823466e38f, mB = -3.402823466e38f;
  int tlA = 0, tlB = 0;
  int ts = ic * TPC, te = ts + TPC;
  if (te > NT) te = NT;
  #pragma unroll 1
  for (int tile = ts; tile < te; ++tile) {
    int r = tile * 32 + ln;
    union { bfrag f; unsigned u[4]; } A0, A1, A2;
    if constexpr (PRE) {
      size_t aoff = (size_t)r * 16 + hf * 8;   // r < NPAD always
      A0.f = *(const bfrag*)(es0 + aoff);
      A1.f = *(const bfrag*)(es1 + aoff);
      A2.f = *(const bfrag*)(es2 + aoff);
    } else {
      float4 e0, e1;
      if (r < NITEMS) {
        const float4* p = (const float4*)(emb + (size_t)r * 16 + hf * 8);
        e0 = p[0]; e1 = p[1];
      } else {
        e0 = make_float4(-128.f, -128.f, -128.f, -128.f);
        e1 = e0;
      }
      float ev[8] = {e0.x, e0.y, e0.z, e0.w, e1.x, e1.y, e1.z, e1.w};
      #pragma unroll
      for (int j = 0; j < 4; ++j)
        split3(ev[2 * j], ev[2 * j + 1], A0.u[j], A1.u[j], A2.u[j]);
    }
    f32x16 accA, accB;
    #pragma unroll
    for (int i = 0; i < 16; ++i) { accA[i] = -SHIFT; accB[i] = -SHIFT; }
    // product order per chain identical to verified round-5 kernel
    accA = __builtin_amdgcn_mfma_f32_32x32x16_bf16(A1.f, bA1, accA, 0, 0, 0);
    accB = __builtin_amdgcn_mfma_f32_32x32x16_bf16(A1.f, bB1, accB, 0, 0, 0);
    accA = __builtin_amdgcn_mfma_f32_32x32x16_bf16(A2.f, bA0, accA, 0, 0, 0);
    accB = __builtin_amdgcn_mfma_f32_32x32x16_bf16(A2.f, bB0, accB, 0, 0, 0);
    accA = __builtin_amdgcn_mfma_f32_32x32x16_bf16(A0.f, bA2, accA, 0, 0, 0);
    accB = __builtin_amdgcn_mfma_f32_32x32x16_bf16(A0.f, bB2, accB, 0, 0, 0);
    accA = __builtin_amdgcn_mfma_f32_32x32x16_bf16(A1.f, bA0, accA, 0, 0, 0);
    accB = __builtin_amdgcn_mfma_f32_32x32x16_bf16(A1.f, bB0, accB, 0, 0, 0);
    accA = __builtin_amdgcn_mfma_f32_32x32x16_bf16(A0.f, bA1, accA, 0, 0, 0);
    accB = __builtin_amdgcn_mfma_f32_32x32x16_bf16(A0.f, bB1, accB, 0, 0, 0);
    accA = __builtin_amdgcn_mfma_f32_32x32x16_bf16(A0.f, bA0, accA, 0, 0, 0);
    accB = __builtin_amdgcn_mfma_f32_32x32x16_bf16(A0.f, bB0, accB, 0, 0, 0);
    float tmA, tmB;
    {
      float f1 = FMAX3(accA[0], accA[1], accA[2]);
      float f2 = FMAX3(accA[3], accA[4], accA[5]);
      float f3 = FMAX3(accA[6], accA[7], accA[8]);
      float f4 = FMAX3(accA[9], accA[10], accA[11]);
      float f5 = FMAX3(accA[12], accA[13], accA[14]);
      float g1 = FMAX3(f1, f2, accA[15]);
      float g2 = fmaxf(f3, f4);
      tmA = FMAX3(g1, g2, f5);
    }
    {
      float f1 = FMAX3(accB[0], accB[1], accB[2]);
      float f2 = FMAX3(accB[3], accB[4], accB[5]);
      float f3 = FMAX3(accB[6], accB[7], accB[8]);
      float f4 = FMAX3(accB[9], accB[10], accB[11]);
      float f5 = FMAX3(accB[12], accB[13], accB[14]);
      float g1 = FMAX3(f1, f2, accB[15]);
      float g2 = fmaxf(f3, f4);
      tmB = FMAX3(g1, g2, f5);
    }
    if (tmA > mA) { mA = tmA; tlA = tile; }   // strict > : lowest tile on ties
    if (tmB > mB) { mB = tmB; tlB = tile; }
    #pragma unroll
    for (int i = 0; i < 16; ++i) {
      sA += __builtin_amdgcn_exp2f(accA[i]);
      sB += __builtin_amdgcn_exp2f(accB[i]);
    }
  }
  // lanes (l, l+32) hold the same col, disjoint row sets
  sA += __shfl_xor(sA, 32);
  sB += __shfl_xor(sB, 32);
  {
    float om = __shfl_xor(mA, 32); int ot = __shfl_xor(tlA, 32);
    if (om > mA || (om == mA && ot < tlA)) { mA = om; tlA = ot; }
  }
  {
    float om = __shfl_xor(mB, 32); int ot = __shfl_xor(tlB, 32);
    if (om > mB || (om == mB && ot < tlB)) { mB = om; tlB = ot; }
  }
  if (hf == 0) {
    ps[ic * NCOL + colA] = sA;
    ps[ic * NCOL + colB] = sB;
    unsigned long long kA = ((unsigned long long)mono32(mA) << 32) | (unsigned)(2047 - tlA);
    unsigned long long kB = ((unsigned long long)mono32(mB) << 32) | (unsigned)(2047 - tlB);
    if (kA > keys[colA]) atomicMax(&keys[colA], kA);   // load-filter then atomic
    if (kB > keys[colB]) atomicMax(&keys[colB], kB);
  }
}

// Argmax fixup: grid (80 col-groups, 8 residue classes), 1 wave each. Re-runs the
// ONE winning tile per col through the bit-identical chain; lowest bit-matching row.
template<int PRE>
__global__ __launch_bounds__(64) void argmax_fix(const unsigned long long* __restrict__ keys,
    const unsigned short* __restrict__ rx0, const unsigned short* __restrict__ rx1,
    const unsigned short* __restrict__ rx2, const float* __restrict__ emb,
    const unsigned short* __restrict__ es0, const unsigned short* __restrict__ es1,
    const unsigned short* __restrict__ es2, float* __restrict__ out) {
  int l = threadIdx.x, ln = l & 31, hf = l >> 5;
  int g = blockIdx.x, k = blockIdx.y;
  int col = g * 32 + ln;
  unsigned long long key = keys[col];
  unsigned um = (unsigned)(key >> 32);
  int tl = 2047 - (int)(key & 0xFFFFFFFFu);
  size_t off = (size_t)col * 16 + hf * 8;
  bfrag b0 = *(const bfrag*)(rx0 + off);
  bfrag b1 = *(const bfrag*)(rx1 + off);
  bfrag b2 = *(const bfrag*)(rx2 + off);
  bool done = ((tl & 7) != k);
  while (true) {
    int tsel = done ? 0x7FFFFFFF : tl;
    #pragma unroll
    for (int o = 32; o > 0; o >>= 1) tsel = min(tsel, __shfl_xor(tsel, o));
    if (tsel == 0x7FFFFFFF) break;
    int r = tsel * 32 + ln;
    union { bfrag f; unsigned u[4]; } A0, A1, A2;
    if constexpr (PRE) {
      size_t aoff = (size_t)r * 16 + hf * 8;
      A0.f = *(const bfrag*)(es0 + aoff);
      A1.f = *(const bfrag*)(es1 + aoff);
      A2.f = *(const bfrag*)(es2 + aoff);
    } else {
      float4 e0, e1;
      if (r < NITEMS) {
        const float4* p = (const float4*)(emb + (size_t)r * 16 + hf * 8);
        e0 = p[0]; e1 = p[1];
      } else {
        e0 = make_float4(-128.f, -128.f, -128.f, -128.f);
        e1 = e0;
      }
      float ev[8] = {e0.x, e0.y, e0.z, e0.w, e1.x, e1.y, e1.z, e1.w};
      #pragma unroll
      for (int j = 0; j < 4; ++j)
        split3(ev[2 * j], ev[2 * j + 1], A0.u[j], A1.u[j], A2.u[j]);
    }
    f32x16 acc;
    #pragma unroll
    for (int i = 0; i < 16; ++i) acc[i] = -SHIFT;
    acc = __builtin_amdgcn_mfma_f32_32x32x16_bf16(A1.f, b1, acc, 0, 0, 0);
    acc = __builtin_amdgcn_mfma_f32_32x32x16_bf16(A2.f, b0, acc, 0, 0, 0);
    acc = __builtin_amdgcn_mfma_f32_32x32x16_bf16(A0.f, b2, acc, 0, 0, 0);
    acc = __builtin_amdgcn_mfma_f32_32x32x16_bf16(A1.f, b0, acc, 0, 0, 0);
    acc = __builtin_amdgcn_mfma_f32_32x32x16_bf16(A0.f, b1, acc, 0, 0, 0);
    acc = __builtin_amdgcn_mfma_f32_32x32x16_bf16(A0.f, b0, acc, 0, 0, 0);
    if (!done && tl == tsel) {
      int best = 0x7FFFFFFF;
      #pragma unroll
      for (int g2 = 0; g2 < 4; ++g2)
        #pragma unroll
        for (int i = 0; i < 4; ++i) {
          float x = acc[g2 * 4 + i];
          int row = 8 * g2 + 4 * hf + i;
          if (mono32(x) == um) best = min(best, tsel * 32 + row);
        }
      int ob = __shfl_xor(best, 32);
      best = min(best, ob);
      if (hf == 0) out[OUT_RS + col] = (float)best;
      done = true;
    }
  }
}

// Combine chunk S-partials (shared fixed shift) + slate prob.
__global__ __launch_bounds__(256) void score_final(const float* __restrict__ psg,
    const float* __restrict__ rx, const float* __restrict__ emb,
    const int* __restrict__ slate, float* __restrict__ out) {
  int tid = blockIdx.x * 256 + threadIdx.x;
  if (tid >= BATCH * 10) return;
  int b = tid / 10, k = tid % 10;
  float S = 0.f;
  for (int c = 0; c < IC; ++c) S += psg[c * NCOL + tid];   // col == tid
  int it = slate[b * 10 + k];
  const float* er = emb + (size_t)it * 16;
  const float* rr = rx + b * 160 + k * 16;  // pre-scaled by LOG2E
  float xs = -SHIFT;
  #pragma unroll
  for (int e = 0; e < 16; ++e) xs = fmaf(rr[e], er[e], xs);
  out[OUT_RR + b * 10 + k] = __builtin_amdgcn_exp2f(xs) / S;
}

extern "C" void kernel_launch(void* const* d_in, const int* in_sizes, int n_in,
                              void* d_out, int out_size, void* d_ws, size_t ws_size,
                              hipStream_t stream) {
  const int* user_repr = (const int*)d_in[0];
  const int* slate = (const int*)d_in[1];
  const float* resp = (const float*)d_in[2];
  const float* eps = (const float*)d_in[3];
  const float* emb = (const float*)d_in[4];
  const float* W_enc = (const float*)d_in[5];
  const float* b_enc = (const float*)d_in[6];
  const float* W_mu = (const float*)d_in[7];
  const float* b_mu = (const float*)d_in[8];
  const float* W_lv = (const float*)d_in[9];
  const float* b_lv = (const float*)d_in[10];
  const float* W_d1 = (const float*)d_in[11];
  const float* b_d1 = (const float*)d_in[12];
  const float* W_d2 = (const float*)d_in[13];
  const float* b_d2 = (const float*)d_in[14];
  float* out = (float*)d_out;
  float* ws = (float*)d_ws;

  float* x    = ws + WS_X;
  float* dz   = ws + WS_DZ;
  float* p2   = ws + WS_P2;
  float* pp   = ws + WS_PP;
  float* part = ws + WS_PART;
  float* ps   = ws + WS_PS;
  unsigned long long* keys = (unsigned long long*)(ws + WS_KEY);
  float* rx   = ws + WS_RX;
  unsigned short* rx0 = (unsigned short*)(ws + WS_RXS0);
  unsigned short* rx1 = (unsigned short*)(ws + WS_RXS1);
  unsigned short* rx2 = (unsigned short*)(ws + WS_RXS2);
  unsigned short* es0 = (unsigned short*)(ws + WS_ES0);
  unsigned short* es1 = (unsigned short*)(ws + WS_ES1);
  unsigned short* es2 = (unsigned short*)(ws + WS_ES2);
  bool pre = ws_size >= WS_NEED;

  if (pre)
    emb_split<<<1563, 256, 0, stream>>>(emb, (unsigned*)es0, (unsigned*)es1, (unsigned*)es2);
  pool_mfma<<<dim3(2, KCH), 256, 0, stream>>>(user_repr, emb, pp);
  build_x<<<256, 256, 0, stream>>>(pp, slate, resp, emb, x, dz);
  gemm64<<<dim3(8, 4, 4), 256, 0, stream>>>(x, W_enc, part, 256, 512, 1200, 300);
  mulv_z_kernel<<<256, 128, 0, stream>>>(part, b_enc, W_mu, b_mu, W_lv, b_lv, eps, out, dz);
  gemm64<<<dim3(8, 4, 4), 256, 0, stream>>>(dz, W_d1, part, 256, 512, 1104, 276);
  gemm_d2<<<dim3(3, 4, 8), 256, 0, stream>>>(part, b_d1, W_d2, p2);
  rx_prep<<<256, 256, 0, stream>>>(p2, b_d2, rx, rx0, rx1, rx2, keys);
  if (pre) {
    score_mfma<1><<<dim3(10, IC), 256, 0, stream>>>(emb, rx0, rx1, rx2, es0, es1, es2, ps, keys);
    argmax_fix<1><<<dim3(80, 8), 64, 0, stream>>>(keys, rx0, rx1, rx2, emb, es0, es1, es2, out);
  } else {
    score_mfma<0><<<dim3(10, IC), 256, 0, stream>>>(emb, rx0, rx1, rx2, es0, es1, es2, ps, keys);
    argmax_fix<0><<<dim3(80, 8), 64, 0, stream>>>(keys, rx0, rx1, rx2, emb, es0, es1, es2, out);
  }
  score_final<<<10, 256, 0, stream>>>(ps, rx, emb, slate, out);
}

// Round 12
// 259.927 us; speedup vs baseline: 1.0420x; 1.0420x over previous
//
#include <hip/hip_runtime.h>

// Problem constants
#define NITEMS 50000
#define EMBD   16
#define NSLATE 10
#define HIDD   512
#define LATD   64
#define RESPD  1024
#define BATCH  256
#define KCH    120   // pool k-chunks: 3125 ksteps (=50000/16) split 5x27 + 115x26
#define LOG2E  1.44269504088896340736f
#define SHIFT  64.0f  // fixed log2-domain shift: s = sum exp2(x*log2e - 64)

// MFMA scoring: logits = rx[2560x16] @ emb^T[16x50000] via v_mfma_f32_32x32x16_bf16.
#define NCOL   2560   // BATCH*NSLATE output columns
#define NT     1563   // ceil(50000/32) item tiles (last tile has 16 pad rows)
#define NPAD   50016  // NT*32 padded items
#define IC     224    // item chunks (grid.y)
#define TPC    7      // tiles per chunk: 224*7 = 1568 >= 1563

// d_out layout (float): z_mean[256*64] | z_log_var[256*64] | recon_slate[256*10] | recon_resp[256*10]
#define OUT_ZM 0
#define OUT_ZLV 16384
#define OUT_RS 32768
#define OUT_RR 35328

// ws layout (floats), with time-overlays (all dispatches stream-ordered):
//   [0 .. 589824)        x[307200] + dz[282624]  (build_x -> enc / d1)
//                        OVERLAY p2[8*40960=327680] (gemm_d2 -> rx_prep)
//   [0 .. 573440)        OVERLAY score S-partials ps[224*2560] (score_mfma -> score_final)
//   [573440 .. 578560)   OVERLAY keys[2560 u64] packed (mono(m)<<32 | 2047-tile)
//   [589824 .. 1114112)  pool partials pp [120kc*256*17 = 522240] (pool_mfma -> build_x)
//                        OVERLAY part[4*131072] (small-ws fallback MLP partials)
//   [1114112 .. 1155072) rx[40960] f32, LOG2E-scaled (rx_prep -> score_final)
//   [1155072 .. 1216512) rx bf16 3-way split rx0/rx1/rx2 [3*40960 ushort]
//   --- extension (guarded by ws_size >= WS_NEED; round-9 profile: harness fills a
//       256 MiB d_ws) ---
//   [1216512 .. 1616640) es0 [50016*16 ushort] emb split level 0 (emb_split -> score/fix)
//   [1616640 .. 2016768) es1
//   [2016768 .. 2416896) es2
//   [2416896 .. 3465472) part8 [8*131072] MLP split-K partials (z=8 -> 256 blocks)
// WS_NEED = 3465472 floats = 13.9 MB; fallback = round-9 inline-split + z=4 path.
// ROUND-11 BUG FIX: z=8 kChunk MUST be a multiple of 16 (was 150/138 -> chunk
// starts misaligned, float4 guard straddled ke: boundary elements double-counted
// across z-partials + over-read past K -> rx perturbed -> argmax flips. 160/144
// restore the alignment invariant that made the z=4 path (300/276, 4-aligned ks,
// no straddle) correct.
#define WS_X    0
#define WS_DZ   307200
#define WS_P2   0
#define WS_PS   0
#define WS_KEY  573440
#define WS_PP   589824
#define WS_PART 589824
#define WS_RX   1114112
#define WS_RXS0 1155072
#define WS_RXS1 1175552
#define WS_RXS2 1196032
#define WS_ES0  1216512
#define WS_ES1  1616640
#define WS_ES2  2016768
#define WS_P8   2416896
#define WS_NEED ((size_t)3465472 * 4)

typedef __attribute__((ext_vector_type(8))) short bfrag;    // 8 bf16 = 4 VGPR (A/B operand)
typedef __attribute__((ext_vector_type(16))) float f32x16;  // C/D operand

// round-to-nearest-even f32 -> bf16, returned as f32 with low mantissa zeroed
__device__ __forceinline__ float bfround(float v) {
  unsigned u = __float_as_uint(v);
  unsigned r = (u + 0x7FFFu + ((u >> 16) & 1u)) & 0xFFFF0000u;
  return __uint_as_float(r);
}

// monotone bijection f32 -> u32 (x < y  <=>  mono(x) < mono(y))
__device__ __forceinline__ unsigned mono32(float f) {
  unsigned u = __float_as_uint(f);
  return (u & 0x80000000u) ? ~u : (u | 0x80000000u);
}

#define FMAX3(a, b, c) fmaxf(fmaxf((a), (b)), (c))

// Exact truncation 3-way split of one f32 pair into packed bf16 words.
__device__ __forceinline__ void split3(float v0, float v1,
    unsigned& o0, unsigned& o1, unsigned& o2) {
  unsigned u0 = __float_as_uint(v0), u1 = __float_as_uint(v1);
  o0 = (u0 >> 16) | (u1 & 0xFFFF0000u);
  float r0 = v0 - __uint_as_float(u0 & 0xFFFF0000u);   // exact
  float r1 = v1 - __uint_as_float(u1 & 0xFFFF0000u);   // exact
  unsigned w0 = __float_as_uint(r0), w1 = __float_as_uint(r1);
  o1 = (w0 >> 16) | (w1 & 0xFFFF0000u);
  float q0 = r0 - __uint_as_float(w0 & 0xFFFF0000u);   // exact, fits bf16
  float q1 = r1 - __uint_as_float(w1 & 0xFFFF0000u);   // exact, fits bf16
  o2 = (__float_as_uint(q0) >> 16) | (__float_as_uint(q1) & 0xFFFF0000u);
}

// Precompute emb 3-way split, padded to NPAD rows with -128 (split: -128, 0, 0).
__global__ __launch_bounds__(256) void emb_split(const float* __restrict__ emb,
    unsigned* __restrict__ es0, unsigned* __restrict__ es1, unsigned* __restrict__ es2) {
  int idx = blockIdx.x * 256 + threadIdx.x;   // pair index: item*8 + jp
  if (idx >= NPAD * 8) return;
  int item = idx >> 3, jp = idx & 7;
  float v0 = -128.f, v1 = -128.f;
  if (item < NITEMS) {
    v0 = emb[(size_t)item * 16 + 2 * jp];
    v1 = emb[(size_t)item * 16 + 2 * jp + 1];
  }
  unsigned o0, o1, o2;
  split3(v0, v1, o0, o1, o2);
  es0[idx] = o0; es1[idx] = o1; es2[idx] = o2;
}

// MFMA pooling: user[256][17] = U[256x50000] @ [emb | 1] via v_mfma_f32_32x32x16_bf16.
__global__ __launch_bounds__(256) void pool_mfma(const int* __restrict__ u,
    const float* __restrict__ emb, float* __restrict__ pp) {
  int t = threadIdx.x;
  int w = t >> 6, l = t & 63;
  int ln = l & 31, hf = l >> 5;
  int rt = blockIdx.x * 4 + w;     // 0..7 row tile (32 batches each)
  int kc = blockIdx.y;             // 0..119 k-chunks
  int row = rt * 32 + ln;
  int ks = kc * 26 + min(kc, 5);
  int ke = ks + 26 + (kc < 5 ? 1 : 0);
  const int* uRow = u + (size_t)row * NITEMS + hf * 8;
  f32x16 acc;
  #pragma unroll
  for (int i = 0; i < 16; ++i) acc[i] = 0.f;
  #pragma unroll 1
  for (int k0 = ks; k0 < ke; ++k0) {
    const int4* ap = (const int4*)(uRow + k0 * 16);
    int4 a0 = ap[0], a1 = ap[1];
    union { bfrag f; unsigned ui[4]; } A;
    A.ui[0] = (a0.x ? 0x3F80u : 0u) | (a0.y ? 0x3F800000u : 0u);
    A.ui[1] = (a0.z ? 0x3F80u : 0u) | (a0.w ? 0x3F800000u : 0u);
    A.ui[2] = (a1.x ? 0x3F80u : 0u) | (a1.y ? 0x3F800000u : 0u);
    A.ui[3] = (a1.z ? 0x3F80u : 0u) | (a1.w ? 0x3F800000u : 0u);
    union { bfrag f; unsigned ui[4]; } B0, B1, B2;
    if (ln < 16) {
      const float* ep = emb + (size_t)(k0 * 16 + hf * 8) * 16 + ln;
      #pragma unroll
      for (int j = 0; j < 4; ++j)
        split3(ep[(2 * j) * 16], ep[(2 * j + 1) * 16], B0.ui[j], B1.ui[j], B2.ui[j]);
    } else {
      unsigned c0 = (ln == 16) ? 0x3F803F80u : 0u;
      #pragma unroll
      for (int j = 0; j < 4; ++j) { B0.ui[j] = c0; B1.ui[j] = 0u; B2.ui[j] = 0u; }
    }
    acc = __builtin_amdgcn_mfma_f32_32x32x16_bf16(A.f, B2.f, acc, 0, 0, 0);
    acc = __builtin_amdgcn_mfma_f32_32x32x16_bf16(A.f, B1.f, acc, 0, 0, 0);
    acc = __builtin_amdgcn_mfma_f32_32x32x16_bf16(A.f, B0.f, acc, 0, 0, 0);
  }
  if (ln < 17) {
    float* dst = pp + (size_t)kc * 4352 + (size_t)(rt * 32) * 17 + ln;
    #pragma unroll
    for (int g = 0; g < 4; ++g)
      #pragma unroll
      for (int q = 0; q < 4; ++q) {
        int r = q + 8 * g + 4 * hf;
        dst[r * 17] = acc[g * 4 + q];
      }
  }
}

// Sum 120 k-chunk partials per b; build x = [slate(160)|user(16)|resp(1024)],
// dz[64:1104] = [user|resp].
__global__ __launch_bounds__(256) void build_x(const float* __restrict__ pp,
    const int* __restrict__ slate, const float* __restrict__ resp,
    const float* __restrict__ emb, float* __restrict__ x, float* __restrict__ dz) {
  __shared__ float fin[17];
  int b = blockIdx.x, t = threadIdx.x;
  if (t < 17) {
    float a = 0.f;
    const float* p = pp + (size_t)b * 17 + t;
    #pragma unroll 8
    for (int kc = 0; kc < KCH; ++kc) a += p[(size_t)kc * 4352];
    fin[t] = a;
  }
  __syncthreads();
  float inv = 1.0f / fin[16];
  if (t < 16) {
    float uv = fin[t] * inv;
    x[b * 1200 + 160 + t] = uv;
    dz[b * 1104 + 64 + t] = uv;
  }
  if (t >= 32 && t < 192) {
    int i = t - 32;
    int k = i >> 4, e = i & 15;
    int it = slate[b * 10 + k];
    x[b * 1200 + i] = emb[(size_t)it * 16 + e];
  }
  for (int i = t; i < 1024; i += 256) {
    float r = resp[b * 1024 + i];
    x[b * 1200 + 176 + i] = r;
    dz[b * 1104 + 80 + i] = r;
  }
}

// Split-K partial GEMM: P[z][M,N] = A[M,ks:ke] @ B[N,ks:ke]^T
// REQUIREMENT: kChunk % 16 == 0 (chunk starts 16-aligned -> float4 guard never
// straddles ke and never over-reads K; see round-11 bug note in header).
__global__ __launch_bounds__(256) void gemm64(const float* __restrict__ A,
    const float* __restrict__ B, float* __restrict__ P, int M, int N, int K, int kChunk) {
  __shared__ float As[16][68];  // As[kk][m]
  __shared__ float Bs[16][68];  // Bs[kk][n]
  int tid = threadIdx.x;
  int m0 = blockIdx.y * 64, n0 = blockIdx.x * 64;
  int ks = blockIdx.z * kChunk;
  int ke = ks + kChunk; if (ke > K) ke = K;
  int sr = tid >> 2;          // 0..63
  int sc = (tid & 3) * 4;     // 0,4,8,12
  int tx = tid & 15, ty = tid >> 4;
  float acc[4][4];
  #pragma unroll
  for (int i = 0; i < 4; ++i)
    #pragma unroll
    for (int j = 0; j < 4; ++j) acc[i][j] = 0.f;
  for (int k0 = ks; k0 < ke; k0 += 16) {
    float4 av = make_float4(0.f, 0.f, 0.f, 0.f);
    float4 bv = make_float4(0.f, 0.f, 0.f, 0.f);
    if (k0 + sc < ke)
      av = *(const float4*)(A + (size_t)(m0 + sr) * K + k0 + sc);
    if (k0 + sc < ke && n0 + sr < N)
      bv = *(const float4*)(B + (size_t)(n0 + sr) * K + k0 + sc);
    __syncthreads();
    As[sc][sr] = av.x; As[sc + 1][sr] = av.y; As[sc + 2][sr] = av.z; As[sc + 3][sr] = av.w;
    Bs[sc][sr] = bv.x; Bs[sc + 1][sr] = bv.y; Bs[sc + 2][sr] = bv.z; Bs[sc + 3][sr] = bv.w;
    __syncthreads();
    #pragma unroll
    for (int kk = 0; kk < 16; ++kk) {
      float4 a4 = *(const float4*)&As[kk][4 * ty];
      float4 b4 = *(const float4*)&Bs[kk][4 * tx];
      float a[4] = {a4.x, a4.y, a4.z, a4.w};
      float b[4] = {b4.x, b4.y, b4.z, b4.w};
      #pragma unroll
      for (int i = 0; i < 4; ++i)
        #pragma unroll
        for (int j = 0; j < 4; ++j) acc[i][j] = fmaf(a[i], b[j], acc[i][j]);
    }
  }
  float* Pz = P + (size_t)blockIdx.z * M * N;
  #pragma unroll
  for (int i = 0; i < 4; ++i) {
    int m = m0 + 4 * ty + i, n = n0 + 4 * tx;
    if (n < N)
      *(float4*)(Pz + (size_t)m * N + n) = make_float4(acc[i][0], acc[i][1], acc[i][2], acc[i][3]);
  }
}

// h = relu(sum_s part[s] + b_enc); z_mean/z_log_var -> out; z -> dz[0:64]
__global__ __launch_bounds__(128) void mulv_z_kernel(const float* __restrict__ part,
    const float* __restrict__ benc,
    const float* __restrict__ Wmu, const float* __restrict__ bmu,
    const float* __restrict__ Wlv, const float* __restrict__ blv,
    const float* __restrict__ eps, float* __restrict__ out, float* __restrict__ dz,
    int ns) {
  __shared__ __align__(16) float hs[512];
  __shared__ float zms[64], zlvs[64];
  int b = blockIdx.x, t = threadIdx.x;
  for (int i = t; i < 512; i += 128) {
    float a = benc[i];
    for (int s = 0; s < ns; ++s) a += part[(size_t)s * 131072 + b * 512 + i];
    hs[i] = fmaxf(a, 0.f);
  }
  __syncthreads();
  const float* Wr = (t < 64) ? (Wmu + (size_t)t * 512) : (Wlv + (size_t)(t - 64) * 512);
  float bias = (t < 64) ? bmu[t] : blv[t - 64];
  const float4* w4 = (const float4*)Wr;
  const float4* h4 = (const float4*)hs;
  float a0 = 0.f, a1 = 0.f, a2 = 0.f, a3 = 0.f;
  #pragma unroll 4
  for (int i = 0; i < 128; ++i) {
    float4 w = w4[i], hv = h4[i];
    a0 = fmaf(w.x, hv.x, a0); a1 = fmaf(w.y, hv.y, a1);
    a2 = fmaf(w.z, hv.z, a2); a3 = fmaf(w.w, hv.w, a3);
  }
  float acc = (a0 + a1) + (a2 + a3) + bias;
  if (t < 64) { out[OUT_ZM + b * 64 + t] = acc; zms[t] = acc; }
  else        { out[OUT_ZLV + b * 64 + (t - 64)] = acc; zlvs[t - 64] = acc; }
  __syncthreads();
  if (t < 64) {
    float zv = fmaf(eps[b * 64 + t], __builtin_amdgcn_exp2f(0.7213475204444817f * zlvs[t]), zms[t]);
    dz[b * 1104 + t] = zv;
  }
}

// d2 split-K GEMM with reduce-on-load: A[m][k] = relu(sum_s part[s][m*512+k] + b_d1[k]),
// P2[z] = A[:, z*64:(z+1)*64] @ W_d2[:, same]^T. Grid (3,4,8).
__global__ __launch_bounds__(256) void gemm_d2(const float* __restrict__ part,
    const float* __restrict__ bd1, const float* __restrict__ W, float* __restrict__ p2,
    int ns) {
  __shared__ float As[16][68];
  __shared__ float Bs[16][68];
  const int N = 160;
  int tid = threadIdx.x;
  int m0 = blockIdx.y * 64, n0 = blockIdx.x * 64;
  int ks = blockIdx.z * 64, ke = ks + 64;
  int sr = tid >> 2, sc = (tid & 3) * 4;
  int tx = tid & 15, ty = tid >> 4;
  float acc[4][4];
  #pragma unroll
  for (int i = 0; i < 4; ++i)
    #pragma unroll
    for (int j = 0; j < 4; ++j) acc[i][j] = 0.f;
  for (int k0 = ks; k0 < ke; k0 += 16) {
    int col = k0 + sc;
    const float* p = part + (size_t)(m0 + sr) * 512 + col;
    float4 av = *(const float4*)(bd1 + col);
    for (int s = 0; s < ns; ++s) {
      float4 a = *(const float4*)(p + (size_t)s * 131072);
      av.x += a.x; av.y += a.y; av.z += a.z; av.w += a.w;
    }
    av.x = fmaxf(av.x, 0.f);
    av.y = fmaxf(av.y, 0.f);
    av.z = fmaxf(av.z, 0.f);
    av.w = fmaxf(av.w, 0.f);
    float4 bv = make_float4(0.f, 0.f, 0.f, 0.f);
    if (n0 + sr < N)
      bv = *(const float4*)(W + (size_t)(n0 + sr) * 512 + col);
    __syncthreads();
    As[sc][sr] = av.x; As[sc + 1][sr] = av.y; As[sc + 2][sr] = av.z; As[sc + 3][sr] = av.w;
    Bs[sc][sr] = bv.x; Bs[sc + 1][sr] = bv.y; Bs[sc + 2][sr] = bv.z; Bs[sc + 3][sr] = bv.w;
    __syncthreads();
    #pragma unroll
    for (int kk = 0; kk < 16; ++kk) {
      float4 a4 = *(const float4*)&As[kk][4 * ty];
      float4 b4 = *(const float4*)&Bs[kk][4 * tx];
      float a[4] = {a4.x, a4.y, a4.z, a4.w};
      float b[4] = {b4.x, b4.y, b4.z, b4.w};
      #pragma unroll
      for (int i = 0; i < 4; ++i)
        #pragma unroll
        for (int j = 0; j < 4; ++j) acc[i][j] = fmaf(a[i], b[j], acc[i][j]);
    }
  }
  float* Pz = p2 + (size_t)blockIdx.z * 40960;
  #pragma unroll
  for (int i = 0; i < 4; ++i) {
    int m = m0 + 4 * ty + i, n = n0 + 4 * tx;
    if (n < N)
      *(float4*)(Pz + (size_t)m * 160 + n) = make_float4(acc[i][0], acc[i][1], acc[i][2], acc[i][3]);
  }
}

// Finish d2: rx = relu(sum_z p2 + b_d2) * LOG2E, 3-way bf16 split, zero argmax keys.
__global__ __launch_bounds__(256) void rx_prep(const float* __restrict__ p2,
    const float* __restrict__ bd2, float* __restrict__ rx,
    unsigned short* __restrict__ rx0, unsigned short* __restrict__ rx1,
    unsigned short* __restrict__ rx2, unsigned long long* __restrict__ keys) {
  int b = blockIdx.x, t = threadIdx.x;
  if (t < 10) keys[b * 10 + t] = 0ULL;
  if (t >= 160) return;
  float a = bd2[t];
  #pragma unroll
  for (int z = 0; z < 8; ++z) a += p2[(size_t)z * 40960 + b * 160 + t];
  float v = fmaxf(a, 0.f) * LOG2E;
  rx[b * 160 + t] = v;
  int col = b * 10 + (t >> 4), e = t & 15;
  float f0 = bfround(v);
  float d1 = v - f0;            // exact (Sterbenz)
  float f1 = bfround(d1);
  float d2 = d1 - f1;           // exact
  float f2 = bfround(d2);
  rx0[col * 16 + e] = (unsigned short)(__float_as_uint(f0) >> 16);
  rx1[col * 16 + e] = (unsigned short)(__float_as_uint(f1) >> 16);
  rx2[col * 16 + e] = (unsigned short)(__float_as_uint(f2) >> 16);
}

// MFMA scoring: per wave TWO 32-col groups, TPC tiles/chunk, IC=224 chunks.
// PRE=1: A-fragments from precomputed es arrays with software pipeline (prefetch
// tile t+1's 3x16B loads before tile t's MFMA chain) + zacc constant-C.
// PRE=0: round-9 inline-split fallback (bitwise-identical values either way).
template<int PRE>
__global__ __launch_bounds__(256) void score_mfma(const float* __restrict__ emb,
    const unsigned short* __restrict__ rx0, const unsigned short* __restrict__ rx1,
    const unsigned short* __restrict__ rx2,
    const unsigned short* __restrict__ es0, const unsigned short* __restrict__ es1,
    const unsigned short* __restrict__ es2,
    float* __restrict__ ps, unsigned long long* __restrict__ keys) {
  int t = threadIdx.x;
  int w = t >> 6, l = t & 63;
  int ln = l & 31, hf = l >> 5;
  int pair = blockIdx.x * 4 + w;   // 0..39 column-pair groups
  int ic = blockIdx.y;             // 0..223 item chunks
  int colA = pair * 64 + ln;       // 0..2559
  int colB = colA + 32;
  size_t offA = (size_t)colA * 16 + hf * 8;
  size_t offB = (size_t)colB * 16 + hf * 8;
  bfrag bA0 = *(const bfrag*)(rx0 + offA);
  bfrag bA1 = *(const bfrag*)(rx1 + offA);
  bfrag bA2 = *(const bfrag*)(rx2 + offA);
  bfrag bB0 = *(const bfrag*)(rx0 + offB);
  bfrag bB1 = *(const bfrag*)(rx1 + offB);
  bfrag bB2 = *(const bfrag*)(rx2 + offB);
  f32x16 zacc;
  #pragma unroll
  for (int i = 0; i < 16; ++i) zacc[i] = -SHIFT;
  float sA = 0.f, sB = 0.f;
  float mA = -3.402823466e38f, mB = -3.402823466e38f;
  int tlA = 0, tlB = 0;
  int ts = ic * TPC, te = ts + TPC;
  if (te > NT) te = NT;
  union FU { bfrag f; unsigned u[4]; };
  FU A0c, A1c, A2c;
  if constexpr (PRE) {
    size_t aoff = (size_t)(ts * 32 + ln) * 16 + hf * 8;
    A0c.f = *(const bfrag*)(es0 + aoff);
    A1c.f = *(const bfrag*)(es1 + aoff);
    A2c.f = *(const bfrag*)(es2 + aoff);
  }
  #pragma unroll 1
  for (int tile = ts; tile < te; ++tile) {
    FU A0n, A1n, A2n;
    if constexpr (PRE) {
      if (tile + 1 < te) {   // prefetch next tile's fragments under this tile's MFMAs
        size_t aoff = (size_t)((tile + 1) * 32 + ln) * 16 + hf * 8;
        A0n.f = *(const bfrag*)(es0 + aoff);
        A1n.f = *(const bfrag*)(es1 + aoff);
        A2n.f = *(const bfrag*)(es2 + aoff);
      }
    } else {
      int r = tile * 32 + ln;
      float4 e0, e1;
      if (r < NITEMS) {
        const float4* p = (const float4*)(emb + (size_t)r * 16 + hf * 8);
        e0 = p[0]; e1 = p[1];
      } else {
        e0 = make_float4(-128.f, -128.f, -128.f, -128.f);
        e1 = e0;
      }
      float ev[8] = {e0.x, e0.y, e0.z, e0.w, e1.x, e1.y, e1.z, e1.w};
      #pragma unroll
      for (int j = 0; j < 4; ++j)
        split3(ev[2 * j], ev[2 * j + 1], A0c.u[j], A1c.u[j], A2c.u[j]);
    }
    f32x16 accA, accB;
    // product order per chain identical to verified round-5 kernel; zacc as C of
    // the first MFMA == init-to--SHIFT (bitwise identical)
    accA = __builtin_amdgcn_mfma_f32_32x32x16_bf16(A1c.f, bA1, zacc, 0, 0, 0);
    accB = __builtin_amdgcn_mfma_f32_32x32x16_bf16(A1c.f, bB1, zacc, 0, 0, 0);
    accA = __builtin_amdgcn_mfma_f32_32x32x16_bf16(A2c.f, bA0, accA, 0, 0, 0);
    accB = __builtin_amdgcn_mfma_f32_32x32x16_bf16(A2c.f, bB0, accB, 0, 0, 0);
    accA = __builtin_amdgcn_mfma_f32_32x32x16_bf16(A0c.f, bA2, accA, 0, 0, 0);
    accB = __builtin_amdgcn_mfma_f32_32x32x16_bf16(A0c.f, bB2, accB, 0, 0, 0);
    accA = __builtin_amdgcn_mfma_f32_32x32x16_bf16(A1c.f, bA0, accA, 0, 0, 0);
    accB = __builtin_amdgcn_mfma_f32_32x32x16_bf16(A1c.f, bB0, accB, 0, 0, 0);
    accA = __builtin_amdgcn_mfma_f32_32x32x16_bf16(A0c.f, bA1, accA, 0, 0, 0);
    accB = __builtin_amdgcn_mfma_f32_32x32x16_bf16(A0c.f, bB1, accB, 0, 0, 0);
    accA = __builtin_amdgcn_mfma_f32_32x32x16_bf16(A0c.f, bA0, accA, 0, 0, 0);
    accB = __builtin_amdgcn_mfma_f32_32x32x16_bf16(A0c.f, bB0, accB, 0, 0, 0);
    float tmA, tmB;
    {
      float f1 = FMAX3(accA[0], accA[1], accA[2]);
      float f2 = FMAX3(accA[3], accA[4], accA[5]);
      float f3 = FMAX3(accA[6], accA[7], accA[8]);
      float f4 = FMAX3(accA[9], accA[10], accA[11]);
      float f5 = FMAX3(accA[12], accA[13], accA[14]);
      float g1 = FMAX3(f1, f2, accA[15]);
      float g2 = fmaxf(f3, f4);
      tmA = FMAX3(g1, g2, f5);
    }
    {
      float f1 = FMAX3(accB[0], accB[1], accB[2]);
      float f2 = FMAX3(accB[3], accB[4], accB[5]);
      float f3 = FMAX3(accB[6], accB[7], accB[8]);
      float f4 = FMAX3(accB[9], accB[10], accB[11]);
      float f5 = FMAX3(accB[12], accB[13], accB[14]);
      float g1 = FMAX3(f1, f2, accB[15]);
      float g2 = fmaxf(f3, f4);
      tmB = FMAX3(g1, g2, f5);
    }
    if (tmA > mA) { mA = tmA; tlA = tile; }   // strict > : lowest tile on ties
    if (tmB > mB) { mB = tmB; tlB = tile; }
    #pragma unroll
    for (int i = 0; i < 16; ++i) {
      sA += __builtin_amdgcn_exp2f(accA[i]);
      sB += __builtin_amdgcn_exp2f(accB[i]);
    }
    if constexpr (PRE) { A0c = A0n; A1c = A1n; A2c = A2n; }
  }
  // lanes (l, l+32) hold the same col, disjoint row sets
  sA += __shfl_xor(sA, 32);
  sB += __shfl_xor(sB, 32);
  {
    float om = __shfl_xor(mA, 32); int ot = __shfl_xor(tlA, 32);
    if (om > mA || (om == mA && ot < tlA)) { mA = om; tlA = ot; }
  }
  {
    float om = __shfl_xor(mB, 32); int ot = __shfl_xor(tlB, 32);
    if (om > mB || (om == mB && ot < tlB)) { mB = om; tlB = ot; }
  }
  if (hf == 0) {
    ps[ic * NCOL + colA] = sA;
    ps[ic * NCOL + colB] = sB;
    unsigned long long kA = ((unsigned long long)mono32(mA) << 32) | (unsigned)(2047 - tlA);
    unsigned long long kB = ((unsigned long long)mono32(mB) << 32) | (unsigned)(2047 - tlB);
    if (kA > keys[colA]) atomicMax(&keys[colA], kA);   // load-filter then atomic
    if (kB > keys[colB]) atomicMax(&keys[colB], kB);
  }
}

// Argmax fixup: re-runs the ONE winning tile per col through the bit-identical
// chain; lowest bit-matching row -> recon_slate.
template<int PRE>
__global__ __launch_bounds__(64) void argmax_fix(const unsigned long long* __restrict__ keys,
    const unsigned short* __restrict__ rx0, const unsigned short* __restrict__ rx1,
    const unsigned short* __restrict__ rx2, const float* __restrict__ emb,
    const unsigned short* __restrict__ es0, const unsigned short* __restrict__ es1,
    const unsigned short* __restrict__ es2, float* __restrict__ out) {
  int l = threadIdx.x, ln = l & 31, hf = l >> 5;
  int g = blockIdx.x, k = blockIdx.y;
  int col = g * 32 + ln;
  unsigned long long key = keys[col];
  unsigned um = (unsigned)(key >> 32);
  int tl = 2047 - (int)(key & 0xFFFFFFFFu);
  size_t off = (size_t)col * 16 + hf * 8;
  bfrag b0 = *(const bfrag*)(rx0 + off);
  bfrag b1 = *(const bfrag*)(rx1 + off);
  bfrag b2 = *(const bfrag*)(rx2 + off);
  bool done = ((tl & 7) != k);
  while (true) {
    int tsel = done ? 0x7FFFFFFF : tl;
    #pragma unroll
    for (int o = 32; o > 0; o >>= 1) tsel = min(tsel, __shfl_xor(tsel, o));
    if (tsel == 0x7FFFFFFF) break;
    int r = tsel * 32 + ln;
    union { bfrag f; unsigned u[4]; } A0, A1, A2;
    if constexpr (PRE) {
      size_t aoff = (size_t)r * 16 + hf * 8;
      A0.f = *(const bfrag*)(es0 + aoff);
      A1.f = *(const bfrag*)(es1 + aoff);
      A2.f = *(const bfrag*)(es2 + aoff);
    } else {
      float4 e0, e1;
      if (r < NITEMS) {
        const float4* p = (const float4*)(emb + (size_t)r * 16 + hf * 8);
        e0 = p[0]; e1 = p[1];
      } else {
        e0 = make_float4(-128.f, -128.f, -128.f, -128.f);
        e1 = e0;
      }
      float ev[8] = {e0.x, e0.y, e0.z, e0.w, e1.x, e1.y, e1.z, e1.w};
      #pragma unroll
      for (int j = 0; j < 4; ++j)
        split3(ev[2 * j], ev[2 * j + 1], A0.u[j], A1.u[j], A2.u[j]);
    }
    f32x16 acc;
    #pragma unroll
    for (int i = 0; i < 16; ++i) acc[i] = -SHIFT;
    acc = __builtin_amdgcn_mfma_f32_32x32x16_bf16(A1.f, b1, acc, 0, 0, 0);
    acc = __builtin_amdgcn_mfma_f32_32x32x16_bf16(A2.f, b0, acc, 0, 0, 0);
    acc = __builtin_amdgcn_mfma_f32_32x32x16_bf16(A0.f, b2, acc, 0, 0, 0);
    acc = __builtin_amdgcn_mfma_f32_32x32x16_bf16(A1.f, b0, acc, 0, 0, 0);
    acc = __builtin_amdgcn_mfma_f32_32x32x16_bf16(A0.f, b1, acc, 0, 0, 0);
    acc = __builtin_amdgcn_mfma_f32_32x32x16_bf16(A0.f, b0, acc, 0, 0, 0);
    if (!done && tl == tsel) {
      int best = 0x7FFFFFFF;
      #pragma unroll
      for (int g2 = 0; g2 < 4; ++g2)
        #pragma unroll
        for (int i = 0; i < 4; ++i) {
          float x = acc[g2 * 4 + i];
          int row = 8 * g2 + 4 * hf + i;
          if (mono32(x) == um) best = min(best, tsel * 32 + row);
        }
      int ob = __shfl_xor(best, 32);
      best = min(best, ob);
      if (hf == 0) out[OUT_RS + col] = (float)best;
      done = true;
    }
  }
}

// Combine chunk S-partials (shared fixed shift) + slate prob.
__global__ __launch_bounds__(256) void score_final(const float* __restrict__ psg,
    const float* __restrict__ rx, const float* __restrict__ emb,
    const int* __restrict__ slate, float* __restrict__ out) {
  int tid = blockIdx.x * 256 + threadIdx.x;
  if (tid >= BATCH * 10) return;
  int b = tid / 10, k = tid % 10;
  float S = 0.f;
  for (int c = 0; c < IC; ++c) S += psg[c * NCOL + tid];   // col == tid
  int it = slate[b * 10 + k];
  const float* er = emb + (size_t)it * 16;
  const float* rr = rx + b * 160 + k * 16;  // pre-scaled by LOG2E
  float xs = -SHIFT;
  #pragma unroll
  for (int e = 0; e < 16; ++e) xs = fmaf(rr[e], er[e], xs);
  out[OUT_RR + b * 10 + k] = __builtin_amdgcn_exp2f(xs) / S;
}

extern "C" void kernel_launch(void* const* d_in, const int* in_sizes, int n_in,
                              void* d_out, int out_size, void* d_ws, size_t ws_size,
                              hipStream_t stream) {
  const int* user_repr = (const int*)d_in[0];
  const int* slate = (const int*)d_in[1];
  const float* resp = (const float*)d_in[2];
  const float* eps = (const float*)d_in[3];
  const float* emb = (const float*)d_in[4];
  const float* W_enc = (const float*)d_in[5];
  const float* b_enc = (const float*)d_in[6];
  const float* W_mu = (const float*)d_in[7];
  const float* b_mu = (const float*)d_in[8];
  const float* W_lv = (const float*)d_in[9];
  const float* b_lv = (const float*)d_in[10];
  const float* W_d1 = (const float*)d_in[11];
  const float* b_d1 = (const float*)d_in[12];
  const float* W_d2 = (const float*)d_in[13];
  const float* b_d2 = (const float*)d_in[14];
  float* out = (float*)d_out;
  float* ws = (float*)d_ws;

  float* x    = ws + WS_X;
  float* dz   = ws + WS_DZ;
  float* p2   = ws + WS_P2;
  float* pp   = ws + WS_PP;
  float* part = ws + WS_PART;
  float* ps   = ws + WS_PS;
  unsigned long long* keys = (unsigned long long*)(ws + WS_KEY);
  float* rx   = ws + WS_RX;
  unsigned short* rx0 = (unsigned short*)(ws + WS_RXS0);
  unsigned short* rx1 = (unsigned short*)(ws + WS_RXS1);
  unsigned short* rx2 = (unsigned short*)(ws + WS_RXS2);
  unsigned short* es0 = (unsigned short*)(ws + WS_ES0);
  unsigned short* es1 = (unsigned short*)(ws + WS_ES1);
  unsigned short* es2 = (unsigned short*)(ws + WS_ES2);
  float* part8 = ws + WS_P8;
  bool pre = ws_size >= WS_NEED;

  if (pre)
    emb_split<<<1563, 256, 0, stream>>>(emb, (unsigned*)es0, (unsigned*)es1, (unsigned*)es2);
  pool_mfma<<<dim3(2, KCH), 256, 0, stream>>>(user_repr, emb, pp);
  build_x<<<256, 256, 0, stream>>>(pp, slate, resp, emb, x, dz);
  if (pre) {
    // split-K z=8 -> 256 blocks = 1/CU. kChunk MUST be %16==0 (round-11 bug):
    // enc K=1200 -> 160 (z7 gets 80); d1 K=1104 -> 144 (z7 gets 96).
    gemm64<<<dim3(8, 4, 8), 256, 0, stream>>>(x, W_enc, part8, 256, 512, 1200, 160);
    mulv_z_kernel<<<256, 128, 0, stream>>>(part8, b_enc, W_mu, b_mu, W_lv, b_lv, eps, out, dz, 8);
    gemm64<<<dim3(8, 4, 8), 256, 0, stream>>>(dz, W_d1, part8, 256, 512, 1104, 144);
    gemm_d2<<<dim3(3, 4, 8), 256, 0, stream>>>(part8, b_d1, W_d2, p2, 8);
  } else {
    gemm64<<<dim3(8, 4, 4), 256, 0, stream>>>(x, W_enc, part, 256, 512, 1200, 300);
    mulv_z_kernel<<<256, 128, 0, stream>>>(part, b_enc, W_mu, b_mu, W_lv, b_lv, eps, out, dz, 4);
    gemm64<<<dim3(8, 4, 4), 256, 0, stream>>>(dz, W_d1, part, 256, 512, 1104, 276);
    gemm_d2<<<dim3(3, 4, 8), 256, 0, stream>>>(part, b_d1, W_d2, p2, 4);
  }
  rx_prep<<<256, 256, 0, stream>>>(p2, b_d2, rx, rx0, rx1, rx2, keys);
  if (pre) {
    score_mfma<1><<<dim3(10, IC), 256, 0, stream>>>(emb, rx0, rx1, rx2, es0, es1, es2, ps, keys);
    argmax_fix<1><<<dim3(80, 8), 64, 0, stream>>>(keys, rx0, rx1, rx2, emb, es0, es1, es2, out);
  } else {
    score_mfma<0><<<dim3(10, IC), 256, 0, stream>>>(emb, rx0, rx1, rx2, es0, es1, es2, ps, keys);
    argmax_fix<0><<<dim3(80, 8), 64, 0, stream>>>(keys, rx0, rx1, rx2, emb, es0, es1, es2, out);
  }
  score_final<<<10, 256, 0, stream>>>(ps, rx, emb, slate, out);
}